// Round 1
// 237.274 us; speedup vs baseline: 1.0118x; 1.0118x over previous
//
#include <hip/hip_runtime.h>
#include <stdint.h>

// GCN: 3x GraphConv (left norm) + heads, bf16 internal / fp32 accumulate.
// This revision: fused aggregate+GEMM per layer (LDS A-tile, XOR-swizzled),
// fused preprocessing pairs, pi head via plain store. 8 dispatches total.

#define INF 128
#define HIDF 256
#define TM 32   // output rows per fused block

typedef __attribute__((ext_vector_type(8))) short bf16x8;   // 8 bf16 (4 VGPRs)
typedef __attribute__((ext_vector_type(4))) float f32x4;

__device__ __forceinline__ float bf_lo(uint32_t u) {
    union { uint32_t i; float f; } x; x.i = u << 16; return x.f;
}
__device__ __forceinline__ float bf_hi(uint32_t u) {
    union { uint32_t i; float f; } x; x.i = u & 0xffff0000u; return x.f;
}
__device__ __forceinline__ uint16_t f2bf(float f) {   // round-to-nearest-even
    union { float f; uint32_t i; } x; x.f = f;
    uint32_t r = x.i + 0x7fffu + ((x.i >> 16) & 1u);
    return (uint16_t)(r >> 16);
}
__device__ __forceinline__ uint32_t pack2(float a, float b) {
    return (uint32_t)f2bf(a) | ((uint32_t)f2bf(b) << 16);
}

// ---------------- preprocessing ----------------

// blocks [0, eb): degree histograms.  blocks [eb, ...): W1/W2/W3 -> swizzled
// bf16 panels (independent of the graph -> fused into one launch).
// Bsw layout: [k/32][n][k%32]
__global__ void hist_prepw(const int* __restrict__ src, const int* __restrict__ dst,
                           int* __restrict__ odeg, int* __restrict__ counts,
                           const float* __restrict__ W1, const float* __restrict__ W2,
                           const float* __restrict__ W3,
                           uint16_t* __restrict__ W1s, uint16_t* __restrict__ W2s,
                           uint16_t* __restrict__ W3s, int E, int eb) {
    int b = blockIdx.x;
    if (b < eb) {
        int e = b * 256 + threadIdx.x;
        if (e < E) {
            atomicAdd(&odeg[src[e]], 1);
            atomicAdd(&counts[dst[e]], 1);
        }
        return;
    }
    int idx = (b - eb) * 256 + threadIdx.x;
    if (idx < INF * HIDF) {
        int k = idx >> 8, n = idx & 255;
        W1s[((size_t)(k >> 5) * 256 + n) * 32 + (k & 31)] = f2bf(W1[idx]);
        return;
    }
    idx -= INF * HIDF;
    if (idx < HIDF * HIDF) {
        int k = idx >> 8, n = idx & 255;
        W2s[((size_t)(k >> 5) * 256 + n) * 32 + (k & 31)] = f2bf(W2[idx]);
        return;
    }
    idx -= HIDF * HIDF;
    if (idx < HIDF * HIDF) {
        int k = idx >> 8, n = idx & 255;
        W3s[((size_t)(k >> 5) * 256 + n) * 32 + (k & 31)] = f2bf(W3[idx]);
    }
}

// scan of counts -> offsets[0..n]; also computes inv_deg
__global__ __launch_bounds__(1024) void scan_kernel(const int* __restrict__ counts,
                                                    int* __restrict__ offsets,
                                                    const int* __restrict__ odeg,
                                                    float* __restrict__ inv, int n) {
    __shared__ int partial[1024];
    int tid = threadIdx.x;
    int chunk = (n + 1023) / 1024;
    int start = tid * chunk;
    int s = 0;
    for (int i = 0; i < chunk; i++) {
        int idx = start + i;
        if (idx < n) {
            s += counts[idx];
            int d = odeg[idx];
            inv[idx] = d > 0 ? 1.0f / (float)d : 0.0f;
        }
    }
    partial[tid] = s;
    __syncthreads();
    for (int off = 1; off < 1024; off <<= 1) {
        int v = 0;
        if (tid >= off) v = partial[tid - off];
        __syncthreads();
        partial[tid] += v;
        __syncthreads();
    }
    int run = (tid > 0) ? partial[tid - 1] : 0;
    for (int i = 0; i < chunk; i++) {
        int idx = start + i;
        if (idx < n) { offsets[idx] = run; run += counts[idx]; }
    }
    if (tid == 1023) offsets[n] = partial[1023];
}

// blocks [0, eb): CSR edge build.  blocks [eb, ...): features fp32 -> bf16
// scaled by inv_deg[row] (both depend only on scan -> fused).
__global__ void build_feat(const int* __restrict__ src, const int* __restrict__ dst,
                           const int* __restrict__ offsets, int* __restrict__ cursor,
                           int* __restrict__ ssrc, const float* __restrict__ features,
                           const float* __restrict__ inv, uint16_t* __restrict__ fbf,
                           int E, int eb, int N) {
    int b = blockIdx.x;
    if (b < eb) {
        int e = b * 256 + threadIdx.x;
        if (e < E) {
            int d = dst[e];
            int pos = offsets[d] + atomicAdd(&cursor[d], 1);
            ssrc[pos] = src[e];
        }
        return;
    }
    int idx = (b - eb) * 256 + threadIdx.x;
    int nc = N * (INF / 4);
    if (idx < nc) {
        int base = idx * 4;
        int row = base >> 7;                // /128
        float s = inv[row];
        float4 v = *(const float4*)&features[base];
        ushort4 o;
        o.x = f2bf(v.x * s); o.y = f2bf(v.y * s);
        o.z = f2bf(v.z * s); o.w = f2bf(v.w * s);
        *(ushort4*)&fbf[base] = o;
    }
}

// ---------------- fused layer 1: aggregate(128-wide) + GEMM K=128 ----------------
// Block: 32 rows x 256 cols, 8 waves (512 thr). Wave quarters gather 4 edges in
// flight; LDS A-tile XOR-swizzled (byte ^= (row&7)<<4) so MFMA ds_read_b128 at
// 256B row stride is conflict-free (2-way).
__global__ __launch_bounds__(512) void fused_l1(
    const uint16_t* __restrict__ hs, const int* __restrict__ offsets,
    const int* __restrict__ ssrc, const uint16_t* __restrict__ Bsw,
    const float* __restrict__ bias, const float* __restrict__ inv,
    uint16_t* __restrict__ C, int M) {
    __shared__ uint16_t At[TM * INF];      // 8 KB, swizzled
    const int lane = threadIdx.x & 63, wid = threadIdx.x >> 6;
    {
        const int q = lane >> 4, l16 = lane & 15;
        const size_t col = (size_t)l16 * 8;
        for (int nd = 0; nd < 4; nd++) {
            const int rt = wid * 4 + nd;
            const int node = blockIdx.x * TM + rt;
            float a0 = 0, a1 = 0, a2 = 0, a3 = 0, a4 = 0, a5 = 0, a6 = 0, a7 = 0;
            if (node < M) {
                const int beg = offsets[node], end = offsets[node + 1];
                int e = beg + q;
                for (; e + 4 < end; e += 8) {
                    int s0 = ssrc[e], s1 = ssrc[e + 4];
                    uint4 r0 = *(const uint4*)&hs[(size_t)s0 * INF + col];
                    uint4 r1 = *(const uint4*)&hs[(size_t)s1 * INF + col];
                    a0 += bf_lo(r0.x) + bf_lo(r1.x); a1 += bf_hi(r0.x) + bf_hi(r1.x);
                    a2 += bf_lo(r0.y) + bf_lo(r1.y); a3 += bf_hi(r0.y) + bf_hi(r1.y);
                    a4 += bf_lo(r0.z) + bf_lo(r1.z); a5 += bf_hi(r0.z) + bf_hi(r1.z);
                    a6 += bf_lo(r0.w) + bf_lo(r1.w); a7 += bf_hi(r0.w) + bf_hi(r1.w);
                }
                for (; e < end; e += 4) {
                    uint4 t = *(const uint4*)&hs[(size_t)ssrc[e] * INF + col];
                    a0 += bf_lo(t.x); a1 += bf_hi(t.x); a2 += bf_lo(t.y); a3 += bf_hi(t.y);
                    a4 += bf_lo(t.z); a5 += bf_hi(t.z); a6 += bf_lo(t.w); a7 += bf_hi(t.w);
                }
            }
            a0 += __shfl_down(a0, 16, 64); a1 += __shfl_down(a1, 16, 64);
            a2 += __shfl_down(a2, 16, 64); a3 += __shfl_down(a3, 16, 64);
            a4 += __shfl_down(a4, 16, 64); a5 += __shfl_down(a5, 16, 64);
            a6 += __shfl_down(a6, 16, 64); a7 += __shfl_down(a7, 16, 64);
            a0 += __shfl_down(a0, 32, 64); a1 += __shfl_down(a1, 32, 64);
            a2 += __shfl_down(a2, 32, 64); a3 += __shfl_down(a3, 32, 64);
            a4 += __shfl_down(a4, 32, 64); a5 += __shfl_down(a5, 32, 64);
            a6 += __shfl_down(a6, 32, 64); a7 += __shfl_down(a7, 32, 64);
            if (lane < 16) {
                uint4 o;
                o.x = pack2(a0, a1); o.y = pack2(a2, a3);
                o.z = pack2(a4, a5); o.w = pack2(a6, a7);
                const int byte = (rt * 256 + l16 * 16) ^ ((rt & 7) << 4);
                *(uint4*)((char*)At + byte) = o;
            }
        }
    }
    __syncthreads();
    // GEMM: wave wid handles cols [wid*32, wid*32+32)
    const int quad = lane >> 4, l16 = lane & 15;
    const int n0 = wid * 32;
    const int xr = (l16 & 7) << 4;
    f32x4 acc00 = {0, 0, 0, 0}, acc01 = {0, 0, 0, 0};
    f32x4 acc10 = {0, 0, 0, 0}, acc11 = {0, 0, 0, 0};
#pragma unroll
    for (int p = 0; p < INF / 32; p++) {
        bf16x8 a0 = *(const bf16x8*)((const char*)At + ((l16 * 256 + p * 64 + quad * 16) ^ xr));
        bf16x8 a1 = *(const bf16x8*)((const char*)At + (((16 + l16) * 256 + p * 64 + quad * 16) ^ xr));
        bf16x8 b0 = *(const bf16x8*)(Bsw + ((size_t)p * 256 + n0 + l16) * 32 + quad * 8);
        bf16x8 b1 = *(const bf16x8*)(Bsw + ((size_t)p * 256 + n0 + 16 + l16) * 32 + quad * 8);
        acc00 = __builtin_amdgcn_mfma_f32_16x16x32_bf16(a0, b0, acc00, 0, 0, 0);
        acc01 = __builtin_amdgcn_mfma_f32_16x16x32_bf16(a0, b1, acc01, 0, 0, 0);
        acc10 = __builtin_amdgcn_mfma_f32_16x16x32_bf16(a1, b0, acc10, 0, 0, 0);
        acc11 = __builtin_amdgcn_mfma_f32_16x16x32_bf16(a1, b1, acc11, 0, 0, 0);
    }
    const int col0 = n0 + l16, col1 = col0 + 16;
    const float bv0 = bias[col0], bv1 = bias[col1];
#pragma unroll
    for (int reg = 0; reg < 4; reg++) {
        int row0 = blockIdx.x * TM + quad * 4 + reg;
        int row1 = row0 + 16;
        if (row0 < M) {
            float s = inv[row0];
            C[(size_t)row0 * 256 + col0] = f2bf(fmaxf(acc00[reg] + bv0, 0.f) * s);
            C[(size_t)row0 * 256 + col1] = f2bf(fmaxf(acc01[reg] + bv1, 0.f) * s);
        }
        if (row1 < M) {
            float s = inv[row1];
            C[(size_t)row1 * 256 + col0] = f2bf(fmaxf(acc10[reg] + bv0, 0.f) * s);
            C[(size_t)row1 * 256 + col1] = f2bf(fmaxf(acc11[reg] + bv1, 0.f) * s);
        }
    }
}

// ---------------- fused layer 2: aggregate(256-wide) + GEMM K=256 ----------------
__global__ __launch_bounds__(512) void fused_l2(
    const uint16_t* __restrict__ hs, const int* __restrict__ offsets,
    const int* __restrict__ ssrc, const uint16_t* __restrict__ Bsw,
    const float* __restrict__ bias, const float* __restrict__ inv,
    uint16_t* __restrict__ C, int M) {
    __shared__ uint16_t At[TM * HIDF];     // 16 KB, swizzled
    const int lane = threadIdx.x & 63, wid = threadIdx.x >> 6;
    {
        const int half = lane >> 5, l32 = lane & 31;
        const size_t col = (size_t)l32 * 8;
        for (int nd = 0; nd < 4; nd++) {
            const int rt = wid * 4 + nd;
            const int node = blockIdx.x * TM + rt;
            float a0 = 0, a1 = 0, a2 = 0, a3 = 0, a4 = 0, a5 = 0, a6 = 0, a7 = 0;
            if (node < M) {
                const int beg = offsets[node], end = offsets[node + 1];
                int e = beg + half;
                for (; e + 6 < end; e += 8) {
                    int s0 = ssrc[e], s1 = ssrc[e + 2], s2 = ssrc[e + 4], s3 = ssrc[e + 6];
                    uint4 r0 = *(const uint4*)&hs[(size_t)s0 * 256 + col];
                    uint4 r1 = *(const uint4*)&hs[(size_t)s1 * 256 + col];
                    uint4 r2 = *(const uint4*)&hs[(size_t)s2 * 256 + col];
                    uint4 r3 = *(const uint4*)&hs[(size_t)s3 * 256 + col];
                    a0 += bf_lo(r0.x) + bf_lo(r1.x) + bf_lo(r2.x) + bf_lo(r3.x);
                    a1 += bf_hi(r0.x) + bf_hi(r1.x) + bf_hi(r2.x) + bf_hi(r3.x);
                    a2 += bf_lo(r0.y) + bf_lo(r1.y) + bf_lo(r2.y) + bf_lo(r3.y);
                    a3 += bf_hi(r0.y) + bf_hi(r1.y) + bf_hi(r2.y) + bf_hi(r3.y);
                    a4 += bf_lo(r0.z) + bf_lo(r1.z) + bf_lo(r2.z) + bf_lo(r3.z);
                    a5 += bf_hi(r0.z) + bf_hi(r1.z) + bf_hi(r2.z) + bf_hi(r3.z);
                    a6 += bf_lo(r0.w) + bf_lo(r1.w) + bf_lo(r2.w) + bf_lo(r3.w);
                    a7 += bf_hi(r0.w) + bf_hi(r1.w) + bf_hi(r2.w) + bf_hi(r3.w);
                }
                for (; e < end; e += 2) {
                    uint4 t = *(const uint4*)&hs[(size_t)ssrc[e] * 256 + col];
                    a0 += bf_lo(t.x); a1 += bf_hi(t.x); a2 += bf_lo(t.y); a3 += bf_hi(t.y);
                    a4 += bf_lo(t.z); a5 += bf_hi(t.z); a6 += bf_lo(t.w); a7 += bf_hi(t.w);
                }
            }
            a0 += __shfl_down(a0, 32, 64); a1 += __shfl_down(a1, 32, 64);
            a2 += __shfl_down(a2, 32, 64); a3 += __shfl_down(a3, 32, 64);
            a4 += __shfl_down(a4, 32, 64); a5 += __shfl_down(a5, 32, 64);
            a6 += __shfl_down(a6, 32, 64); a7 += __shfl_down(a7, 32, 64);
            if (half == 0) {
                uint4 o;
                o.x = pack2(a0, a1); o.y = pack2(a2, a3);
                o.z = pack2(a4, a5); o.w = pack2(a6, a7);
                const int byte = (rt * 512 + l32 * 16) ^ ((rt & 7) << 4);
                *(uint4*)((char*)At + byte) = o;
            }
        }
    }
    __syncthreads();
    const int quad = lane >> 4, l16 = lane & 15;
    const int n0 = wid * 32;
    const int xr = (l16 & 7) << 4;
    f32x4 acc00 = {0, 0, 0, 0}, acc01 = {0, 0, 0, 0};
    f32x4 acc10 = {0, 0, 0, 0}, acc11 = {0, 0, 0, 0};
#pragma unroll
    for (int p = 0; p < HIDF / 32; p++) {
        bf16x8 a0 = *(const bf16x8*)((const char*)At + ((l16 * 512 + p * 64 + quad * 16) ^ xr));
        bf16x8 a1 = *(const bf16x8*)((const char*)At + (((16 + l16) * 512 + p * 64 + quad * 16) ^ xr));
        bf16x8 b0 = *(const bf16x8*)(Bsw + ((size_t)p * 256 + n0 + l16) * 32 + quad * 8);
        bf16x8 b1 = *(const bf16x8*)(Bsw + ((size_t)p * 256 + n0 + 16 + l16) * 32 + quad * 8);
        acc00 = __builtin_amdgcn_mfma_f32_16x16x32_bf16(a0, b0, acc00, 0, 0, 0);
        acc01 = __builtin_amdgcn_mfma_f32_16x16x32_bf16(a0, b1, acc01, 0, 0, 0);
        acc10 = __builtin_amdgcn_mfma_f32_16x16x32_bf16(a1, b0, acc10, 0, 0, 0);
        acc11 = __builtin_amdgcn_mfma_f32_16x16x32_bf16(a1, b1, acc11, 0, 0, 0);
    }
    const int col0 = n0 + l16, col1 = col0 + 16;
    const float bv0 = bias[col0], bv1 = bias[col1];
#pragma unroll
    for (int reg = 0; reg < 4; reg++) {
        int row0 = blockIdx.x * TM + quad * 4 + reg;
        int row1 = row0 + 16;
        if (row0 < M) {
            float s = inv[row0];
            C[(size_t)row0 * 256 + col0] = f2bf(fmaxf(acc00[reg] + bv0, 0.f) * s);
            C[(size_t)row0 * 256 + col1] = f2bf(fmaxf(acc01[reg] + bv1, 0.f) * s);
        }
        if (row1 < M) {
            float s = inv[row1];
            C[(size_t)row1 * 256 + col0] = f2bf(fmaxf(acc10[reg] + bv0, 0.f) * s);
            C[(size_t)row1 * 256 + col1] = f2bf(fmaxf(acc11[reg] + bv1, 0.f) * s);
        }
    }
}

// ---------------- fused layer 3: aggregate + GEMM + BOTH heads ----------------
// All 256 cols in-block -> pi is a plain store (no atomics, no out memset).
__global__ __launch_bounds__(512) void fused_l3(
    const uint16_t* __restrict__ hs, const int* __restrict__ offsets,
    const int* __restrict__ ssrc, const uint16_t* __restrict__ Bsw,
    const float* __restrict__ b3, const float* __restrict__ Wp,
    const float* __restrict__ bp, float* __restrict__ pi_out,
    float* __restrict__ colsum, int M) {
    __shared__ uint16_t At[TM * HIDF];     // 16 KB, swizzled
    __shared__ float pi_lds[TM][8];
    const int lane = threadIdx.x & 63, wid = threadIdx.x >> 6;
    {
        const int half = lane >> 5, l32 = lane & 31;
        const size_t col = (size_t)l32 * 8;
        for (int nd = 0; nd < 4; nd++) {
            const int rt = wid * 4 + nd;
            const int node = blockIdx.x * TM + rt;
            float a0 = 0, a1 = 0, a2 = 0, a3 = 0, a4 = 0, a5 = 0, a6 = 0, a7 = 0;
            if (node < M) {
                const int beg = offsets[node], end = offsets[node + 1];
                int e = beg + half;
                for (; e + 6 < end; e += 8) {
                    int s0 = ssrc[e], s1 = ssrc[e + 2], s2 = ssrc[e + 4], s3 = ssrc[e + 6];
                    uint4 r0 = *(const uint4*)&hs[(size_t)s0 * 256 + col];
                    uint4 r1 = *(const uint4*)&hs[(size_t)s1 * 256 + col];
                    uint4 r2 = *(const uint4*)&hs[(size_t)s2 * 256 + col];
                    uint4 r3 = *(const uint4*)&hs[(size_t)s3 * 256 + col];
                    a0 += bf_lo(r0.x) + bf_lo(r1.x) + bf_lo(r2.x) + bf_lo(r3.x);
                    a1 += bf_hi(r0.x) + bf_hi(r1.x) + bf_hi(r2.x) + bf_hi(r3.x);
                    a2 += bf_lo(r0.y) + bf_lo(r1.y) + bf_lo(r2.y) + bf_lo(r3.y);
                    a3 += bf_hi(r0.y) + bf_hi(r1.y) + bf_hi(r2.y) + bf_hi(r3.y);
                    a4 += bf_lo(r0.z) + bf_lo(r1.z) + bf_lo(r2.z) + bf_lo(r3.z);
                    a5 += bf_hi(r0.z) + bf_hi(r1.z) + bf_hi(r2.z) + bf_hi(r3.z);
                    a6 += bf_lo(r0.w) + bf_lo(r1.w) + bf_lo(r2.w) + bf_lo(r3.w);
                    a7 += bf_hi(r0.w) + bf_hi(r1.w) + bf_hi(r2.w) + bf_hi(r3.w);
                }
                for (; e < end; e += 2) {
                    uint4 t = *(const uint4*)&hs[(size_t)ssrc[e] * 256 + col];
                    a0 += bf_lo(t.x); a1 += bf_hi(t.x); a2 += bf_lo(t.y); a3 += bf_hi(t.y);
                    a4 += bf_lo(t.z); a5 += bf_hi(t.z); a6 += bf_lo(t.w); a7 += bf_hi(t.w);
                }
            }
            a0 += __shfl_down(a0, 32, 64); a1 += __shfl_down(a1, 32, 64);
            a2 += __shfl_down(a2, 32, 64); a3 += __shfl_down(a3, 32, 64);
            a4 += __shfl_down(a4, 32, 64); a5 += __shfl_down(a5, 32, 64);
            a6 += __shfl_down(a6, 32, 64); a7 += __shfl_down(a7, 32, 64);
            if (half == 0) {
                uint4 o;
                o.x = pack2(a0, a1); o.y = pack2(a2, a3);
                o.z = pack2(a4, a5); o.w = pack2(a6, a7);
                const int byte = (rt * 512 + l32 * 16) ^ ((rt & 7) << 4);
                *(uint4*)((char*)At + byte) = o;
            }
        }
    }
    __syncthreads();
    const int quad = lane >> 4, l16 = lane & 15;
    const int n0 = wid * 32;
    const int xr = (l16 & 7) << 4;
    f32x4 acc00 = {0, 0, 0, 0}, acc01 = {0, 0, 0, 0};
    f32x4 acc10 = {0, 0, 0, 0}, acc11 = {0, 0, 0, 0};
#pragma unroll
    for (int p = 0; p < HIDF / 32; p++) {
        bf16x8 a0 = *(const bf16x8*)((const char*)At + ((l16 * 512 + p * 64 + quad * 16) ^ xr));
        bf16x8 a1 = *(const bf16x8*)((const char*)At + (((16 + l16) * 512 + p * 64 + quad * 16) ^ xr));
        bf16x8 b0 = *(const bf16x8*)(Bsw + ((size_t)p * 256 + n0 + l16) * 32 + quad * 8);
        bf16x8 b1 = *(const bf16x8*)(Bsw + ((size_t)p * 256 + n0 + 16 + l16) * 32 + quad * 8);
        acc00 = __builtin_amdgcn_mfma_f32_16x16x32_bf16(a0, b0, acc00, 0, 0, 0);
        acc01 = __builtin_amdgcn_mfma_f32_16x16x32_bf16(a0, b1, acc01, 0, 0, 0);
        acc10 = __builtin_amdgcn_mfma_f32_16x16x32_bf16(a1, b0, acc10, 0, 0, 0);
        acc11 = __builtin_amdgcn_mfma_f32_16x16x32_bf16(a1, b1, acc11, 0, 0, 0);
    }
    const int col0 = n0 + l16, col1 = col0 + 16;
    const float bv0 = b3[col0], bv1 = b3[col1];
    const float wp0 = Wp[col0], wp1 = Wp[col1];
    float cs0 = 0.f, cs1 = 0.f;
#pragma unroll
    for (int reg = 0; reg < 4; reg++) {
        int r0 = quad * 4 + reg, r1 = r0 + 16;
        int row0 = blockIdx.x * TM + r0;
        int row1 = row0 + 16;
        bool ok0 = row0 < M, ok1 = row1 < M;
        float v00 = acc00[reg] + bv0, v01 = acc01[reg] + bv1;
        float v10 = acc10[reg] + bv0, v11 = acc11[reg] + bv1;
        if (ok0) { cs0 += v00; cs1 += v01; }
        if (ok1) { cs0 += v10; cs1 += v11; }
        float p0 = v00 * wp0 + v01 * wp1;
        float p1 = v10 * wp0 + v11 * wp1;
#pragma unroll
        for (int m = 1; m < 16; m <<= 1) {
            p0 += __shfl_xor(p0, m, 64);
            p1 += __shfl_xor(p1, m, 64);
        }
        if (l16 == 0) {
            pi_lds[r0][wid] = p0;
            pi_lds[r1][wid] = p1;
        }
    }
    cs0 += __shfl_xor(cs0, 16, 64); cs0 += __shfl_xor(cs0, 32, 64);
    cs1 += __shfl_xor(cs1, 16, 64); cs1 += __shfl_xor(cs1, 32, 64);
    if (quad == 0) {
        atomicAdd(&colsum[col0], cs0);
        atomicAdd(&colsum[col1], cs1);
    }
    __syncthreads();
    if (threadIdx.x < TM) {
        int row = blockIdx.x * TM + threadIdx.x;
        if (row < M) {
            float s = 0.f;
#pragma unroll
            for (int w = 0; w < 8; w++) s += pi_lds[threadIdx.x][w];
            pi_out[row] = s + bp[0];
        }
    }
}

// ---------------- V head finisher ----------------
__global__ void v_kernel(const float* __restrict__ colsum, const float* __restrict__ Wv,
                         const float* __restrict__ bv, float* __restrict__ out, float invN) {
    int lane = threadIdx.x;  // 64
    float v = 0.0f;
#pragma unroll
    for (int i = 0; i < 4; i++) v += colsum[lane + 64 * i] * Wv[lane + 64 * i];
#pragma unroll
    for (int o = 32; o > 0; o >>= 1) v += __shfl_down(v, o, 64);
    if (lane == 0) out[0] = v * invN + bv[0];
}

// ---------------- launch ----------------

extern "C" void kernel_launch(void* const* d_in, const int* in_sizes, int n_in,
                              void* d_out, int out_size, void* d_ws, size_t ws_size,
                              hipStream_t stream) {
    const float* features = (const float*)d_in[0];
    const int*   src      = (const int*)d_in[1];
    const int*   dst      = (const int*)d_in[2];
    const float* W1 = (const float*)d_in[3];
    const float* b1 = (const float*)d_in[4];
    const float* W2 = (const float*)d_in[5];
    const float* b2 = (const float*)d_in[6];
    const float* W3 = (const float*)d_in[7];
    const float* b3 = (const float*)d_in[8];
    const float* Wp = (const float*)d_in[9];
    const float* bp = (const float*)d_in[10];
    const float* Wv = (const float*)d_in[11];
    const float* bv = (const float*)d_in[12];
    float* out = (float*)d_out;

    const int N = in_sizes[0] / INF;   // 10000
    const int E = in_sizes[1];         // 320000

    char* p = (char*)d_ws;
    auto alloc = [&](size_t bytes) -> void* {
        void* r = (void*)p;
        p += (bytes + 511) & ~(size_t)511;
        return r;
    };
    // zero-region first (single memset): odeg, counts, cursor, colsum
    int*      odeg    = (int*)alloc((size_t)N * 4);
    int*      counts  = (int*)alloc((size_t)N * 4);
    int*      cursor  = (int*)alloc((size_t)N * 4);
    float*    colsum  = (float*)alloc(HIDF * 4);
    size_t zero_bytes = (size_t)((char*)(colsum + HIDF) - (char*)d_ws);
    // rest
    int*      offsets = (int*)alloc((size_t)(N + 1) * 4);
    int*      ssrc    = (int*)alloc((size_t)E * 4);
    float*    invd    = (float*)alloc((size_t)N * 4);
    uint16_t* fbf     = (uint16_t*)alloc((size_t)N * INF * 2);
    uint16_t* h1      = (uint16_t*)alloc((size_t)N * HIDF * 2);
    uint16_t* h2      = (uint16_t*)alloc((size_t)N * HIDF * 2);
    uint16_t* W1s     = (uint16_t*)alloc((size_t)INF * HIDF * 2);
    uint16_t* W2s     = (uint16_t*)alloc((size_t)HIDF * HIDF * 2);
    uint16_t* W3s     = (uint16_t*)alloc((size_t)HIDF * HIDF * 2);

    hipMemsetAsync(d_ws, 0, zero_bytes, stream);

    const int eb = (E + 255) / 256;
    const int wb = (INF * HIDF + 2 * HIDF * HIDF + 255) / 256;
    hist_prepw<<<eb + wb, 256, 0, stream>>>(src, dst, odeg, counts,
                                            W1, W2, W3, W1s, W2s, W3s, E, eb);
    scan_kernel<<<1, 1024, 0, stream>>>(counts, offsets, odeg, invd, N);
    const int fb = (N * (INF / 4) + 255) / 256;
    build_feat<<<eb + fb, 256, 0, stream>>>(src, dst, offsets, cursor, ssrc,
                                            features, invd, fbf, E, eb, N);

    const int nblk = (N + TM - 1) / TM;   // 313
    fused_l1<<<nblk, 512, 0, stream>>>(fbf, offsets, ssrc, W1s, b1, invd, h1, N);
    fused_l2<<<nblk, 512, 0, stream>>>(h1, offsets, ssrc, W2s, b2, invd, h2, N);
    fused_l3<<<nblk, 512, 0, stream>>>(h2, offsets, ssrc, W3s, b3, Wp, bp, out, colsum, N);

    v_kernel<<<1, 64, 0, stream>>>(colsum, Wv, bv, out + N, 1.0f / (float)N);
}